// Round 12
// baseline (337.409 us; speedup 1.0000x reference)
//
#include <hip/hip_runtime.h>

// may_alias types for all LDS/global reinterpret accesses
typedef __bf16 bf16v8 __attribute__((ext_vector_type(8)));
typedef bf16v8 bf16x8 __attribute__((may_alias));
typedef unsigned int u32v2 __attribute__((ext_vector_type(2)));
typedef u32v2 u32x2 __attribute__((may_alias));
typedef unsigned short u16v8 __attribute__((ext_vector_type(8)));
typedef u16v8 u16x8 __attribute__((may_alias));
typedef unsigned short u16v;
typedef u16v u16 __attribute__((may_alias));
typedef _Float16 f16v4 __attribute__((ext_vector_type(4)));
typedef f16v4 f16x4 __attribute__((may_alias));
typedef _Float16 f16v;
typedef f16v f16s __attribute__((may_alias));
typedef float f32x4 __attribute__((ext_vector_type(4)));
typedef unsigned int u32;

#define MEMFENCE() asm volatile("" ::: "memory")

union B8 { u32 u[4]; bf16v8 v; };

__device__ __forceinline__ u32 cvtpk(float lo, float hi) {
    u32 r;
    asm("v_cvt_pk_bf16_f32 %0, %1, %2" : "=v"(r) : "v"(lo), "v"(hi));
    return r;
}

__device__ __forceinline__ unsigned short f2b(float f) {
    union { float f; unsigned u; } a; a.f = f;
    unsigned r = a.u + 0x7FFFu + ((a.u >> 16) & 1u);   // RNE
    return (unsigned short)(r >> 16);
}

// ---- weight prep (R1-verbatim) ----
__global__ void prep_weights(const float* __restrict__ Wq,
                             const float* __restrict__ Wkv,
                             const float* __restrict__ Wp,
                             const float* __restrict__ bq,
                             const float* __restrict__ bkv,
                             u16* __restrict__ wt,
                             u16* __restrict__ wpt,
                             float* __restrict__ b_all)
{
    int idx = blockIdx.x * 256 + threadIdx.x;
    if (idx < 196608) {                       // 768*256
        int c = idx >> 8, k = idx & 255;
        float v = (c < 256) ? Wq[k * 256 + c] : Wkv[k * 512 + (c - 256)];
        wt[idx] = f2b(v);
    } else if (idx < 262144) {                // + 256*256
        int j = idx - 196608;
        int c = j >> 8, k = j & 255;
        wpt[j] = f2b(Wp[k * 256 + c]);
    } else if (idx < 262912) {                // + 768 biases
        int i = idx - 262144;
        b_all[i] = (i < 256) ? bq[i] : bkv[i - 256];
    }
}

// ================= Kernel A: QKV projection (R8 phases 1-2, outputs to global) =========
// 1 block = 1 window, 8 waves, wave w = head w. LDS = xs only (32 KiB).
// Output layout per (window b, head h), base = qkv + (b*8+h)*3*2048 elems:
//   Q [64 tok][32 col] row-major (64B rows)   at +0
//   K [64 tok][32 col] row-major              at +2048
//   V^T [32 dh][64 tok] row-major (128B rows) at +4096
__global__ __launch_bounds__(512, 4)
void qkv_proj(const float* __restrict__ x,
              const u16* __restrict__ wt,
              const float* __restrict__ b_all,
              u16* __restrict__ qkv)
{
    __shared__ __align__(16) unsigned char smem[32768];
    const int b   = blockIdx.x;
    const int tid = threadIdx.x;
    const int w   = tid >> 6;
    const int l   = tid & 63;
    const int lr  = l & 15;
    const int lg  = l >> 4;
    const int hc  = w * 32;

    f32x4 zero = {0.f, 0.f, 0.f, 0.f};

    // ---------- stage x -> xs bf16 (R8-verbatim) ----------
    {
        const float* xb = x + (size_t)b * 16384;
#pragma unroll
        for (int it = 0; it < 4; ++it) {
            int g   = it * 512 + tid;
            int row = g >> 5;
            int cg  = g & 31;
            const float4 f0 = *(const float4*)(xb + row * 256 + cg * 8);
            const float4 f1 = *(const float4*)(xb + row * 256 + cg * 8 + 4);
            u16v8 t;
            t[0] = f2b(f0.x); t[1] = f2b(f0.y); t[2] = f2b(f0.z); t[3] = f2b(f0.w);
            t[4] = f2b(f1.x); t[5] = f2b(f1.y); t[6] = f2b(f1.z); t[7] = f2b(f1.w);
            int off = row * 512 + ((cg * 16) ^ ((row & 7) << 4));
            *(u16x8*)(smem + off) = t;
        }
    }
    __syncthreads();

    u16* qb  = qkv + (((size_t)b * 8 + w) * 3) * 2048;
    u16* kb_ = qb + 2048;
    unsigned char* vb = (unsigned char*)(qb + 4096);

    // ---------- QKV (R8-verbatim MFMA loop); outputs straight to global ----------
#pragma unroll
    for (int hf = 0; hf < 2; ++hf) {
        f32x4 qa[2][2], ka[2][2], va[2][2];
#pragma unroll
        for (int t = 0; t < 2; ++t)
#pragma unroll
            for (int tj = 0; tj < 2; ++tj) { qa[t][tj] = zero; ka[t][tj] = zero; va[t][tj] = zero; }
#pragma unroll
        for (int ks = 0; ks < 8; ++ks) {
            bf16v8 af[2];
#pragma unroll
            for (int t = 0; t < 2; ++t) {
                int row = hf * 32 + t * 16 + lr;
                af[t] = *(const bf16x8*)(smem + row * 512 + ((ks * 64 + lg * 16) ^ ((row & 7) << 4)));
            }
            bf16v8 bwq[2], bwk[2], bwv[2];
#pragma unroll
            for (int tj = 0; tj < 2; ++tj) {
                const u16* wp0 = wt + (size_t)(hc + tj * 16 + lr) * 256 + ks * 32 + lg * 8;
                bwq[tj] = *(const bf16x8*)(wp0);
                bwk[tj] = *(const bf16x8*)(wp0 + 256 * 256);
                bwv[tj] = *(const bf16x8*)(wp0 + 512 * 256);
            }
            __builtin_amdgcn_s_setprio(1);
#pragma unroll
            for (int tj = 0; tj < 2; ++tj)
#pragma unroll
                for (int t = 0; t < 2; ++t) {
                    qa[t][tj] = __builtin_amdgcn_mfma_f32_16x16x32_bf16(af[t], bwq[tj], qa[t][tj], 0, 0, 0);
                    ka[t][tj] = __builtin_amdgcn_mfma_f32_16x16x32_bf16(af[t], bwk[tj], ka[t][tj], 0, 0, 0);
                    va[t][tj] = __builtin_amdgcn_mfma_f32_16x16x32_bf16(af[t], bwv[tj], va[t][tj], 0, 0, 0);
                }
            __builtin_amdgcn_s_setprio(0);
        }
        // +bias, write out (Q,K: R8 Q-stage formula to global; V^T: R8 V^T-stage formula)
#pragma unroll
        for (int tj = 0; tj < 2; ++tj) {
            float bqv = b_all[hc + tj * 16 + lr];
            float bkr = b_all[256 + hc + tj * 16 + lr];
            float bvr = b_all[512 + hc + tj * 16 + lr];
#pragma unroll
            for (int t = 0; t < 2; ++t) {
#pragma unroll
                for (int e = 0; e < 4; ++e) {
                    int tok = hf * 32 + t * 16 + lg * 4 + e;
                    qb[tok * 32 + tj * 16 + lr]  = f2b(qa[t][tj][e] + bqv);
                    kb_[tok * 32 + tj * 16 + lr] = f2b(ka[t][tj][e] + bkr);
                }
                int dh   = tj * 16 + lr;
                int tok0 = hf * 32 + t * 16 + lg * 4;
                u32x2 pv2;
                pv2[0] = cvtpk(va[t][tj][0] + bvr, va[t][tj][1] + bvr);
                pv2[1] = cvtpk(va[t][tj][2] + bvr, va[t][tj][3] + bvr);
                *(u32x2*)(vb + dh * 128 + tok0 * 2) = pv2;
            }
        }
    }
}

// ================= Kernel B: attention + output projection =================
// 1 block = 1 window, 8 waves, wave w = head w. QKV frags read DIRECTLY from global
// (coalesced b128; L2/L3-hot). LDS (40 KiB):
//   [0,32768): per-wave 4KB P chunk at w*4096 -> O_lds[64][256] overlay
//   [32768,40960): mask f16 [64 q][64 k'] permuted cols (R8 formula, moff=32768)
__global__ __launch_bounds__(512, 4)
void attn_out(const u16* __restrict__ qkv,
              const float* __restrict__ mask,
              const u16* __restrict__ wpt,
              const float* __restrict__ bp,
              float* __restrict__ out)
{
    __shared__ __align__(16) unsigned char smem[40960];
    const int b   = blockIdx.x;
    const int wdw = b & 255;
    const int tid = threadIdx.x;
    const int w   = tid >> 6;
    const int l   = tid & 63;
    const int lr  = l & 15;
    const int lg  = l >> 4;
    const int chunk = w * 4096;                 // P tile
    const int moff  = 32768;
    const int hc    = w * 32;
    const float scale = 0.17677669529663687f;

    f32x4 zero = {0.f, 0.f, 0.f, 0.f};

    // ---------- mask -> LDS f16 permuted (R8-verbatim, moff moved) ----------
    {
        const float* mb = mask + (size_t)wdw * 4096;
#pragma unroll
        for (int it = 0; it < 8; ++it) {
            int idx = it * 512 + tid;
            int q = idx >> 6, k = idx & 63;
            int colp = (k & 15) * 4 + (k >> 4);
            *(f16s*)(smem + moff + q * 128 + ((colp * 2) ^ ((q & 7) << 4)))
                = (_Float16)mb[idx];
        }
    }
    __syncthreads();   // #1

    const u16* qb  = qkv + (((size_t)b * 8 + w) * 3) * 2048;
    const u16* kb_ = qb + 2048;
    const unsigned char* vb = (const unsigned char*)(qb + 4096);

    // Q A-frags, K B-frags: direct global b128 (per inst: 64 lanes = contiguous 1KB)
    bf16v8 aq[4], bk[4];
#pragma unroll
    for (int ti = 0; ti < 4; ++ti)
        aq[ti] = *(const bf16x8*)(qb + (ti * 16 + lr) * 32 + lg * 8);
#pragma unroll
    for (int tj = 0; tj < 4; ++tj)
        bk[tj] = *(const bf16x8*)(kb_ + (tj * 16 + lr) * 32 + lg * 8);

    // ---------- S = Q K^T + softmax (R8-verbatim) ----------
    f32x4 sH[4][4];
    __builtin_amdgcn_s_setprio(1);
#pragma unroll
    for (int ti = 0; ti < 4; ++ti)
#pragma unroll
        for (int tj = 0; tj < 4; ++tj)
            sH[ti][tj] = __builtin_amdgcn_mfma_f32_16x16x32_bf16(aq[ti], bk[tj], zero, 0, 0, 0);
    __builtin_amdgcn_s_setprio(0);

#pragma unroll
    for (int ti = 0; ti < 4; ++ti)
#pragma unroll
        for (int e = 0; e < 4; ++e) {
            int row = ti * 16 + lg * 4 + e;
            f16v4 mv = *(const f16x4*)(smem + moff + row * 128 + ((lr * 8) ^ ((row & 7) << 4)));
#pragma unroll
            for (int tj = 0; tj < 4; ++tj)
                sH[ti][tj][e] = sH[ti][tj][e] * scale + (float)mv[tj];
        }
    float inv[4][4];
#pragma unroll
    for (int ti = 0; ti < 4; ++ti)
#pragma unroll
        for (int e = 0; e < 4; ++e) {
            float v0 = sH[ti][0][e], v1 = sH[ti][1][e];
            float v2 = sH[ti][2][e], v3 = sH[ti][3][e];
            float m = fmaxf(fmaxf(v0, v1), fmaxf(v2, v3));
#pragma unroll
            for (int d = 1; d < 16; d <<= 1) m = fmaxf(m, __shfl_xor(m, d));
            v0 = __expf(v0 - m); v1 = __expf(v1 - m);
            v2 = __expf(v2 - m); v3 = __expf(v3 - m);
            float s = v0 + v1 + v2 + v3;
#pragma unroll
            for (int d = 1; d < 16; d <<= 1) s += __shfl_xor(s, d);
            inv[ti][e] = 1.0f / s;
            sH[ti][0][e] = v0; sH[ti][1][e] = v1;
            sH[ti][2][e] = v2; sH[ti][3][e] = v3;
        }
    u32 pkP[4][4][2];
#pragma unroll
    for (int ti = 0; ti < 4; ++ti)
#pragma unroll
        for (int tj = 0; tj < 4; ++tj) {
            pkP[ti][tj][0] = cvtpk(sH[ti][tj][0], sH[ti][tj][1]);
            pkP[ti][tj][1] = cvtpk(sH[ti][tj][2], sH[ti][tj][3]);
        }

    // ---------- PV in two k-halves (R8-verbatim; bv direct from global V^T) ----------
    f32x4 oH[4][2];
#pragma unroll
    for (int ti = 0; ti < 4; ++ti)
#pragma unroll
        for (int tjv = 0; tjv < 2; ++tjv) oH[ti][tjv] = zero;
#pragma unroll
    for (int kb2 = 0; kb2 < 2; ++kb2) {
#pragma unroll
        for (int ti = 0; ti < 4; ++ti)
#pragma unroll
            for (int tjh = 0; tjh < 2; ++tjh) {
                int c2 = (tjh * 16 + lr) * 2;
#pragma unroll
                for (int ep = 0; ep < 2; ++ep) {
                    u32 u = pkP[ti][2 * kb2 + tjh][ep];
                    int q0 = ti * 16 + lg * 4 + ep * 2;
                    *(u16*)(smem + chunk + q0 * 64 + (c2 ^ (((q0 >> 1) & 3) << 4))) = (unsigned short)u;
                    *(u16*)(smem + chunk + (q0 + 1) * 64 + (c2 ^ ((((q0 + 1) >> 1) & 3) << 4))) = (unsigned short)(u >> 16);
                }
            }
        MEMFENCE();
        bf16v8 bv[2];
#pragma unroll
        for (int tjv = 0; tjv < 2; ++tjv) {
            int dh = tjv * 16 + lr;
            bv[tjv] = *(const bf16x8*)(vb + dh * 128 + kb2 * 64 + lg * 16);
        }
#pragma unroll
        for (int ti = 0; ti < 4; ++ti) {
            int row = ti * 16 + lr;
            bf16v8 ap = *(const bf16x8*)(smem + chunk + row * 64 + ((lg * 16) ^ (((row >> 1) & 3) << 4)));
            __builtin_amdgcn_s_setprio(1);
#pragma unroll
            for (int tjv = 0; tjv < 2; ++tjv)
                oH[ti][tjv] = __builtin_amdgcn_mfma_f32_16x16x32_bf16(ap, bv[tjv], oH[ti][tjv], 0, 0, 0);
            __builtin_amdgcn_s_setprio(0);
        }
        MEMFENCE();
    }
#pragma unroll
    for (int ti = 0; ti < 4; ++ti)
#pragma unroll
        for (int tjv = 0; tjv < 2; ++tjv)
#pragma unroll
            for (int e = 0; e < 4; ++e)
                oH[ti][tjv][e] *= inv[ti][e];

    __syncthreads();   // #2: all PV done -> chunk region becomes O_lds

    // ---------- stage O -> O_lds[64][256] at base 0 (R8-verbatim) ----------
#pragma unroll
    for (int ti = 0; ti < 4; ++ti)
#pragma unroll
        for (int tjv = 0; tjv < 2; ++tjv)
#pragma unroll
            for (int e = 0; e < 4; ++e) {
                int row = ti * 16 + lg * 4 + e;
                int cg  = hc + tjv * 16 + lr;
                *(u16*)(smem + row * 512 + ((cg * 2) ^ ((row & 7) << 4)))
                    = f2b(oH[ti][tjv][e]);
            }
    __syncthreads();   // #3

    // ---------- output projection (R8-verbatim) ----------
    f32x4 pacc[4][2];
#pragma unroll
    for (int ti = 0; ti < 4; ++ti)
#pragma unroll
        for (int tj = 0; tj < 2; ++tj) pacc[ti][tj] = zero;
#pragma unroll
    for (int ks = 0; ks < 8; ++ks) {
        bf16v8 a_[4];
#pragma unroll
        for (int ti = 0; ti < 4; ++ti) {
            int row = ti * 16 + lr;
            a_[ti] = *(const bf16x8*)(smem + row * 512 + ((ks * 64 + lg * 16) ^ ((row & 7) << 4)));
        }
        bf16v8 bw[2];
#pragma unroll
        for (int tj = 0; tj < 2; ++tj)
            bw[tj] = *(const bf16x8*)(wpt + (size_t)(hc + tj * 16 + lr) * 256 + ks * 32 + lg * 8);
        __builtin_amdgcn_s_setprio(1);
#pragma unroll
        for (int tj = 0; tj < 2; ++tj)
#pragma unroll
            for (int ti = 0; ti < 4; ++ti)
                pacc[ti][tj] = __builtin_amdgcn_mfma_f32_16x16x32_bf16(a_[ti], bw[tj], pacc[ti][tj], 0, 0, 0);
        __builtin_amdgcn_s_setprio(0);
    }
    float* ob = out + (size_t)b * 16384;
#pragma unroll
    for (int tj = 0; tj < 2; ++tj) {
        float bias = bp[hc + tj * 16 + lr];
#pragma unroll
        for (int ti = 0; ti < 4; ++ti)
#pragma unroll
            for (int e = 0; e < 4; ++e) {
                int row = ti * 16 + lg * 4 + e;
                ob[row * 256 + hc + tj * 16 + lr] = pacc[ti][tj][e] + bias;
            }
    }
}

// ================= Fallback: R8 fused kernel (proven 279us) =================
__global__ __launch_bounds__(512, 4)
void fused_win_attn(const float* __restrict__ x,
                    const float* __restrict__ mask,
                    const u16* __restrict__ wt,
                    const u16* __restrict__ wpt,
                    const float* __restrict__ b_all,
                    const float* __restrict__ bp,
                    float* __restrict__ out)
{
    __shared__ __align__(16) unsigned char smem[73728];
    const int b   = blockIdx.x;
    const int wdw = b & 255;
    const int tid = threadIdx.x;
    const int w   = tid >> 6;
    const int l   = tid & 63;
    const int lr  = l & 15;
    const int lg  = l >> 4;
    const int chunk = 32768 + w * 4096;
    const int vtb   = w * 4096;
    const int moff  = 65536;
    const int hc    = w * 32;
    const float scale = 0.17677669529663687f;

    f32x4 zero = {0.f, 0.f, 0.f, 0.f};

    {
        const float* xb = x + (size_t)b * 16384;
#pragma unroll
        for (int it = 0; it < 4; ++it) {
            int g   = it * 512 + tid;
            int row = g >> 5;
            int cg  = g & 31;
            const float4 f0 = *(const float4*)(xb + row * 256 + cg * 8);
            const float4 f1 = *(const float4*)(xb + row * 256 + cg * 8 + 4);
            u16v8 t;
            t[0] = f2b(f0.x); t[1] = f2b(f0.y); t[2] = f2b(f0.z); t[3] = f2b(f0.w);
            t[4] = f2b(f1.x); t[5] = f2b(f1.y); t[6] = f2b(f1.z); t[7] = f2b(f1.w);
            int off = row * 512 + ((cg * 16) ^ ((row & 7) << 4));
            *(u16x8*)(smem + off) = t;
        }
    }
    {
        const float* mb = mask + (size_t)wdw * 4096;
#pragma unroll
        for (int it = 0; it < 8; ++it) {
            int idx = it * 512 + tid;
            int q = idx >> 6, k = idx & 63;
            int colp = (k & 15) * 4 + (k >> 4);
            *(f16s*)(smem + moff + q * 128 + ((colp * 2) ^ ((q & 7) << 4)))
                = (_Float16)mb[idx];
        }
    }
    __syncthreads();

    u32 pkK[2][2][2][2], pkV[2][2][2][2];
#pragma unroll
    for (int hf = 0; hf < 2; ++hf) {
        f32x4 qa[2][2], ka[2][2], va[2][2];
#pragma unroll
        for (int t = 0; t < 2; ++t)
#pragma unroll
            for (int tj = 0; tj < 2; ++tj) { qa[t][tj] = zero; ka[t][tj] = zero; va[t][tj] = zero; }
#pragma unroll
        for (int ks = 0; ks < 8; ++ks) {
            bf16v8 af[2];
#pragma unroll
            for (int t = 0; t < 2; ++t) {
                int row = hf * 32 + t * 16 + lr;
                af[t] = *(const bf16x8*)(smem + row * 512 + ((ks * 64 + lg * 16) ^ ((row & 7) << 4)));
            }
            bf16v8 bwq[2], bwk[2], bwv[2];
#pragma unroll
            for (int tj = 0; tj < 2; ++tj) {
                const u16* wp0 = wt + (size_t)(hc + tj * 16 + lr) * 256 + ks * 32 + lg * 8;
                bwq[tj] = *(const bf16x8*)(wp0);
                bwk[tj] = *(const bf16x8*)(wp0 + 256 * 256);
                bwv[tj] = *(const bf16x8*)(wp0 + 512 * 256);
            }
            __builtin_amdgcn_s_setprio(1);
#pragma unroll
            for (int tj = 0; tj < 2; ++tj)
#pragma unroll
                for (int t = 0; t < 2; ++t) {
                    qa[t][tj] = __builtin_amdgcn_mfma_f32_16x16x32_bf16(af[t], bwq[tj], qa[t][tj], 0, 0, 0);
                    ka[t][tj] = __builtin_amdgcn_mfma_f32_16x16x32_bf16(af[t], bwk[tj], ka[t][tj], 0, 0, 0);
                    va[t][tj] = __builtin_amdgcn_mfma_f32_16x16x32_bf16(af[t], bwv[tj], va[t][tj], 0, 0, 0);
                }
            __builtin_amdgcn_s_setprio(0);
        }
#pragma unroll
        for (int tj = 0; tj < 2; ++tj) {
            float bqv = b_all[hc + tj * 16 + lr];
            float bkr = b_all[256 + hc + tj * 16 + lr];
            float bvr = b_all[512 + hc + tj * 16 + lr];
            int c2 = (tj * 16 + lr) * 2;
#pragma unroll
            for (int t = 0; t < 2; ++t) {
#pragma unroll
                for (int ep = 0; ep < 2; ++ep) {
                    u32 uq = cvtpk(qa[t][tj][2 * ep] + bqv, qa[t][tj][2 * ep + 1] + bqv);
                    int tok0 = hf * 32 + t * 16 + lg * 4 + ep * 2;
                    *(u16*)(smem + chunk + tok0 * 64 + (c2 ^ (((tok0 >> 1) & 3) << 4))) = (unsigned short)uq;
                    *(u16*)(smem + chunk + (tok0 + 1) * 64 + (c2 ^ ((((tok0 + 1) >> 1) & 3) << 4))) = (unsigned short)(uq >> 16);
                }
                pkK[hf][t][tj][0] = cvtpk(ka[t][tj][0] + bkr, ka[t][tj][1] + bkr);
                pkK[hf][t][tj][1] = cvtpk(ka[t][tj][2] + bkr, ka[t][tj][3] + bkr);
                pkV[hf][t][tj][0] = cvtpk(va[t][tj][0] + bvr, va[t][tj][1] + bvr);
                pkV[hf][t][tj][1] = cvtpk(va[t][tj][2] + bvr, va[t][tj][3] + bvr);
            }
        }
    }

    MEMFENCE();
    bf16v8 aq[4];
#pragma unroll
    for (int ti = 0; ti < 4; ++ti) {
        int row = ti * 16 + lr;
        aq[ti] = *(const bf16x8*)(smem + chunk + row * 64 + ((lg * 16) ^ (((row >> 1) & 3) << 4)));
    }
    MEMFENCE();
#pragma unroll
    for (int hf = 0; hf < 2; ++hf)
#pragma unroll
        for (int t = 0; t < 2; ++t)
#pragma unroll
            for (int tj = 0; tj < 2; ++tj) {
                int c2 = (tj * 16 + lr) * 2;
#pragma unroll
                for (int ep = 0; ep < 2; ++ep) {
                    u32 u = pkK[hf][t][tj][ep];
                    int tok0 = hf * 32 + t * 16 + lg * 4 + ep * 2;
                    *(u16*)(smem + chunk + tok0 * 64 + (c2 ^ (((tok0 >> 1) & 3) << 4))) = (unsigned short)u;
                    *(u16*)(smem + chunk + (tok0 + 1) * 64 + (c2 ^ ((((tok0 + 1) >> 1) & 3) << 4))) = (unsigned short)(u >> 16);
                }
            }
    MEMFENCE();
    bf16v8 bk[4];
#pragma unroll
    for (int tj = 0; tj < 4; ++tj) {
        int n = tj * 16 + lr;
        bk[tj] = *(const bf16x8*)(smem + chunk + n * 64 + ((lg * 16) ^ (((n >> 1) & 3) << 4)));
    }

    f32x4 sH[4][4];
    __builtin_amdgcn_s_setprio(1);
#pragma unroll
    for (int ti = 0; ti < 4; ++ti)
#pragma unroll
        for (int tj = 0; tj < 4; ++tj)
            sH[ti][tj] = __builtin_amdgcn_mfma_f32_16x16x32_bf16(aq[ti], bk[tj], zero, 0, 0, 0);
    __builtin_amdgcn_s_setprio(0);

#pragma unroll
    for (int ti = 0; ti < 4; ++ti)
#pragma unroll
        for (int e = 0; e < 4; ++e) {
            int row = ti * 16 + lg * 4 + e;
            f16v4 mv = *(const f16x4*)(smem + moff + row * 128 + ((lr * 8) ^ ((row & 7) << 4)));
#pragma unroll
            for (int tj = 0; tj < 4; ++tj)
                sH[ti][tj][e] = sH[ti][tj][e] * scale + (float)mv[tj];
        }
    float inv[4][4];
#pragma unroll
    for (int ti = 0; ti < 4; ++ti)
#pragma unroll
        for (int e = 0; e < 4; ++e) {
            float v0 = sH[ti][0][e], v1 = sH[ti][1][e];
            float v2 = sH[ti][2][e], v3 = sH[ti][3][e];
            float m = fmaxf(fmaxf(v0, v1), fmaxf(v2, v3));
#pragma unroll
            for (int d = 1; d < 16; d <<= 1) m = fmaxf(m, __shfl_xor(m, d));
            v0 = __expf(v0 - m); v1 = __expf(v1 - m);
            v2 = __expf(v2 - m); v3 = __expf(v3 - m);
            float s = v0 + v1 + v2 + v3;
#pragma unroll
            for (int d = 1; d < 16; d <<= 1) s += __shfl_xor(s, d);
            inv[ti][e] = 1.0f / s;
            sH[ti][0][e] = v0; sH[ti][1][e] = v1;
            sH[ti][2][e] = v2; sH[ti][3][e] = v3;
        }
    u32 pkP[4][4][2];
#pragma unroll
    for (int ti = 0; ti < 4; ++ti)
#pragma unroll
        for (int tj = 0; tj < 4; ++tj) {
            pkP[ti][tj][0] = cvtpk(sH[ti][tj][0], sH[ti][tj][1]);
            pkP[ti][tj][1] = cvtpk(sH[ti][tj][2], sH[ti][tj][3]);
        }

    __syncthreads();

#pragma unroll
    for (int hf = 0; hf < 2; ++hf)
#pragma unroll
        for (int t = 0; t < 2; ++t)
#pragma unroll
            for (int tj = 0; tj < 2; ++tj) {
                int dh = tj * 16 + lr;
                int tok0 = hf * 32 + t * 16 + lg * 4;
                u32x2 pv2; pv2[0] = pkV[hf][t][tj][0]; pv2[1] = pkV[hf][t][tj][1];
                *(u32x2*)(smem + vtb + dh * 128 + ((tok0 * 2) ^ ((dh & 7) << 4))) = pv2;
            }
    MEMFENCE();

    f32x4 oH[4][2];
#pragma unroll
    for (int ti = 0; ti < 4; ++ti)
#pragma unroll
        for (int tjv = 0; tjv < 2; ++tjv) oH[ti][tjv] = zero;
#pragma unroll
    for (int kb = 0; kb < 2; ++kb) {
#pragma unroll
        for (int ti = 0; ti < 4; ++ti)
#pragma unroll
            for (int tjh = 0; tjh < 2; ++tjh) {
                int c2 = (tjh * 16 + lr) * 2;
#pragma unroll
                for (int ep = 0; ep < 2; ++ep) {
                    u32 u = pkP[ti][2 * kb + tjh][ep];
                    int q0 = ti * 16 + lg * 4 + ep * 2;
                    *(u16*)(smem + chunk + q0 * 64 + (c2 ^ (((q0 >> 1) & 3) << 4))) = (unsigned short)u;
                    *(u16*)(smem + chunk + (q0 + 1) * 64 + (c2 ^ ((((q0 + 1) >> 1) & 3) << 4))) = (unsigned short)(u >> 16);
                }
            }
        MEMFENCE();
        bf16v8 bv[2];
#pragma unroll
        for (int tjv = 0; tjv < 2; ++tjv) {
            int dh = tjv * 16 + lr;
            bv[tjv] = *(const bf16x8*)(smem + vtb + dh * 128 + ((kb * 64 + lg * 16) ^ ((dh & 7) << 4)));
        }
#pragma unroll
        for (int ti = 0; ti < 4; ++ti) {
            int row = ti * 16 + lr;
            bf16v8 ap = *(const bf16x8*)(smem + chunk + row * 64 + ((lg * 16) ^ (((row >> 1) & 3) << 4)));
            __builtin_amdgcn_s_setprio(1);
#pragma unroll
            for (int tjv = 0; tjv < 2; ++tjv)
                oH[ti][tjv] = __builtin_amdgcn_mfma_f32_16x16x32_bf16(ap, bv[tjv], oH[ti][tjv], 0, 0, 0);
            __builtin_amdgcn_s_setprio(0);
        }
        MEMFENCE();
    }
#pragma unroll
    for (int ti = 0; ti < 4; ++ti)
#pragma unroll
        for (int tjv = 0; tjv < 2; ++tjv)
#pragma unroll
            for (int e = 0; e < 4; ++e)
                oH[ti][tjv][e] *= inv[ti][e];

    __syncthreads();

#pragma unroll
    for (int ti = 0; ti < 4; ++ti)
#pragma unroll
        for (int tjv = 0; tjv < 2; ++tjv)
#pragma unroll
            for (int e = 0; e < 4; ++e) {
                int row = ti * 16 + lg * 4 + e;
                int cg  = hc + tjv * 16 + lr;
                *(u16*)(smem + row * 512 + ((cg * 2) ^ ((row & 7) << 4)))
                    = f2b(oH[ti][tjv][e]);
            }
    __syncthreads();

    f32x4 pacc[4][2];
#pragma unroll
    for (int ti = 0; ti < 4; ++ti)
#pragma unroll
        for (int tj = 0; tj < 2; ++tj) pacc[ti][tj] = zero;
#pragma unroll
    for (int ks = 0; ks < 8; ++ks) {
        bf16v8 a_[4];
#pragma unroll
        for (int ti = 0; ti < 4; ++ti) {
            int row = ti * 16 + lr;
            a_[ti] = *(const bf16x8*)(smem + row * 512 + ((ks * 64 + lg * 16) ^ ((row & 7) << 4)));
        }
        bf16v8 bw[2];
#pragma unroll
        for (int tj = 0; tj < 2; ++tj)
            bw[tj] = *(const bf16x8*)(wpt + (size_t)(hc + tj * 16 + lr) * 256 + ks * 32 + lg * 8);
        __builtin_amdgcn_s_setprio(1);
#pragma unroll
        for (int tj = 0; tj < 2; ++tj)
#pragma unroll
            for (int ti = 0; ti < 4; ++ti)
                pacc[ti][tj] = __builtin_amdgcn_mfma_f32_16x16x32_bf16(a_[ti], bw[tj], pacc[ti][tj], 0, 0, 0);
        __builtin_amdgcn_s_setprio(0);
    }
    float* ob = out + (size_t)b * 16384;
#pragma unroll
    for (int tj = 0; tj < 2; ++tj) {
        float bias = bp[hc + tj * 16 + lr];
#pragma unroll
        for (int ti = 0; ti < 4; ++ti)
#pragma unroll
            for (int e = 0; e < 4; ++e) {
                int row = ti * 16 + lg * 4 + e;
                ob[row * 256 + hc + tj * 16 + lr] = pacc[ti][tj][e] + bias;
            }
    }
}

extern "C" void kernel_launch(void* const* d_in, const int* in_sizes, int n_in,
                              void* d_out, int out_size, void* d_ws, size_t ws_size,
                              hipStream_t stream) {
    const float* x    = (const float*)d_in[0];
    const float* mask = (const float*)d_in[1];
    const float* Wq   = (const float*)d_in[2];
    const float* bq   = (const float*)d_in[3];
    const float* Wkv  = (const float*)d_in[4];
    const float* bkv  = (const float*)d_in[5];
    const float* Wp   = (const float*)d_in[6];
    const float* bp   = (const float*)d_in[7];
    float* out = (float*)d_out;

    u16*   wt    = (u16*)d_ws;                    // 768*256 bf16
    u16*   wpt   = wt + 768 * 256;                // 256*256 bf16
    float* b_all = (float*)(wpt + 256 * 256);     // 768 f32

    const size_t qkv_off   = 589824;              // bytes (after weights, aligned)
    const size_t qkv_bytes = (size_t)2048 * 8 * 3 * 2048 * 2;  // 201.3 MB
    prep_weights<<<1027, 256, 0, stream>>>(Wq, Wkv, Wp, bq, bkv, wt, wpt, b_all);

    if (ws_size >= qkv_off + qkv_bytes) {
        u16* qkv = (u16*)((unsigned char*)d_ws + qkv_off);
        qkv_proj<<<2048, 512, 0, stream>>>(x, wt, b_all, qkv);
        attn_out<<<2048, 512, 0, stream>>>(qkv, mask, wpt, bp, out);
    } else {
        fused_win_attn<<<2048, 512, 0, stream>>>(x, mask, wt, wpt, b_all, bp, out);
    }
}

// Round 13
// 229.064 us; speedup vs baseline: 1.4730x; 1.4730x over previous
//
#include <hip/hip_runtime.h>

// may_alias types for all LDS/global reinterpret accesses
typedef __bf16 bf16v8 __attribute__((ext_vector_type(8)));
typedef bf16v8 bf16x8 __attribute__((may_alias));
typedef unsigned int u32v2 __attribute__((ext_vector_type(2)));
typedef u32v2 u32x2 __attribute__((may_alias));
typedef unsigned short u16v8 __attribute__((ext_vector_type(8)));
typedef u16v8 u16x8 __attribute__((may_alias));
typedef unsigned short u16v;
typedef u16v u16 __attribute__((may_alias));
typedef _Float16 f16v4 __attribute__((ext_vector_type(4)));
typedef f16v4 f16x4 __attribute__((may_alias));
typedef _Float16 f16v;
typedef f16v f16s __attribute__((may_alias));
typedef float f32x4 __attribute__((ext_vector_type(4)));
typedef unsigned int u32;

#define MEMFENCE() asm volatile("" ::: "memory")

union B8 { u32 u[4]; bf16v8 v; };

__device__ __forceinline__ u32 cvtpk(float lo, float hi) {
    u32 r;
    asm("v_cvt_pk_bf16_f32 %0, %1, %2" : "=v"(r) : "v"(lo), "v"(hi));
    return r;
}

__device__ __forceinline__ unsigned short f2b(float f) {
    union { float f; unsigned u; } a; a.f = f;
    unsigned r = a.u + 0x7FFFu + ((a.u >> 16) & 1u);   // RNE
    return (unsigned short)(r >> 16);
}

// ---- weight prep: FRAGMENT-MAJOR layouts (R13) ----
// wt  [h][m][tj][ks][lane][j]  (8*3*2*8*64*8 = 196608 u16): element =
//     W^T[o = h*32+tj*16+(lane&15)][k = ks*32+(lane>>4)*8+j], m: 0=Q,1=K,2=V
// wpt [h][tj][ks][lane][j]     (8*2*8*64*8 = 65536 u16): same with Wp
// A wave's B-frag load becomes base + blk*512 + l*8 -> lane l reads 16B at
// byte l*16 -> one contiguous 1KB region per instruction (8 full 128B lines,
// vs 16 scattered 64B chunks with the old row-major layout).
__global__ void prep_weights(const float* __restrict__ Wq,
                             const float* __restrict__ Wkv,
                             const float* __restrict__ Wp,
                             const float* __restrict__ bq,
                             const float* __restrict__ bkv,
                             u16* __restrict__ wt,
                             u16* __restrict__ wpt,
                             float* __restrict__ b_all)
{
    int idx = blockIdx.x * 256 + threadIdx.x;
    if (idx < 196608) {
        int h  = idx / 24576;   int r  = idx % 24576;
        int m  = r / 8192;      int r2 = r % 8192;
        int tj = r2 / 4096;     int r3 = r2 % 4096;
        int ks = r3 / 512;      int r4 = r3 % 512;
        int lane = r4 >> 3, j = r4 & 7;
        int o = h * 32 + tj * 16 + (lane & 15);
        int k = ks * 32 + (lane >> 4) * 8 + j;
        float v = (m == 0) ? Wq[k * 256 + o]
                           : Wkv[k * 512 + (m == 1 ? o : 256 + o)];
        wt[idx] = f2b(v);
    } else if (idx < 262144) {
        int f  = idx - 196608;
        int h  = f / 8192;      int r2 = f % 8192;
        int tj = r2 / 4096;     int r3 = r2 % 4096;
        int ks = r3 / 512;      int r4 = r3 % 512;
        int lane = r4 >> 3, j = r4 & 7;
        int o = h * 32 + tj * 16 + (lane & 15);
        int k = ks * 32 + (lane >> 4) * 8 + j;
        wpt[f] = f2b(Wp[k * 256 + o]);
    } else if (idx < 262912) {
        int i = idx - 262144;
        b_all[i] = (i < 256) ? bq[i] : bkv[i - 256];
    }
}

// ================= Kernel A: QKV projection =================
// R12-verbatim except: frag-major weight loads (contiguous 1KB/inst) and
// __launch_bounds__(512,2) -> 96 VGPR so all 6 weight loads stay in flight.
// Output per (window b, head h), base = qkv + (b*8+h)*3*2048 elems:
//   Q [64 tok][32 col] at +0, K at +2048, V^T [32 dh][64 tok] at +4096.
__global__ __launch_bounds__(512, 2)
void qkv_proj(const float* __restrict__ x,
              const u16* __restrict__ wt,
              const float* __restrict__ b_all,
              u16* __restrict__ qkv)
{
    __shared__ __align__(16) unsigned char smem[32768];
    const int b   = blockIdx.x;
    const int tid = threadIdx.x;
    const int w   = tid >> 6;
    const int l   = tid & 63;
    const int lr  = l & 15;
    const int lg  = l >> 4;
    const int hc  = w * 32;

    f32x4 zero = {0.f, 0.f, 0.f, 0.f};

    // ---------- stage x -> xs bf16 (R12-verbatim) ----------
    {
        const float* xb = x + (size_t)b * 16384;
#pragma unroll
        for (int it = 0; it < 4; ++it) {
            int g   = it * 512 + tid;
            int row = g >> 5;
            int cg  = g & 31;
            const float4 f0 = *(const float4*)(xb + row * 256 + cg * 8);
            const float4 f1 = *(const float4*)(xb + row * 256 + cg * 8 + 4);
            u16v8 t;
            t[0] = f2b(f0.x); t[1] = f2b(f0.y); t[2] = f2b(f0.z); t[3] = f2b(f0.w);
            t[4] = f2b(f1.x); t[5] = f2b(f1.y); t[6] = f2b(f1.z); t[7] = f2b(f1.w);
            int off = row * 512 + ((cg * 16) ^ ((row & 7) << 4));
            *(u16x8*)(smem + off) = t;
        }
    }
    __syncthreads();

    u16* qb  = qkv + (((size_t)b * 8 + w) * 3) * 2048;
    u16* kb_ = qb + 2048;
    unsigned char* vb = (unsigned char*)(qb + 4096);
    const u16* whead = wt + (size_t)w * 24576;   // per-head frag block

    // ---------- QKV (R12-verbatim MFMA loop, frag-major weight loads) ----------
#pragma unroll
    for (int hf = 0; hf < 2; ++hf) {
        f32x4 qa[2][2], ka[2][2], va[2][2];
#pragma unroll
        for (int t = 0; t < 2; ++t)
#pragma unroll
            for (int tj = 0; tj < 2; ++tj) { qa[t][tj] = zero; ka[t][tj] = zero; va[t][tj] = zero; }
#pragma unroll
        for (int ks = 0; ks < 8; ++ks) {
            bf16v8 af[2];
#pragma unroll
            for (int t = 0; t < 2; ++t) {
                int row = hf * 32 + t * 16 + lr;
                af[t] = *(const bf16x8*)(smem + row * 512 + ((ks * 64 + lg * 16) ^ ((row & 7) << 4)));
            }
            bf16v8 bwq[2], bwk[2], bwv[2];
#pragma unroll
            for (int tj = 0; tj < 2; ++tj) {
                const u16* wp0 = whead + tj * 4096 + ks * 512 + l * 8;
                bwq[tj] = *(const bf16x8*)(wp0);
                bwk[tj] = *(const bf16x8*)(wp0 + 8192);
                bwv[tj] = *(const bf16x8*)(wp0 + 16384);
            }
            __builtin_amdgcn_s_setprio(1);
#pragma unroll
            for (int tj = 0; tj < 2; ++tj)
#pragma unroll
                for (int t = 0; t < 2; ++t) {
                    qa[t][tj] = __builtin_amdgcn_mfma_f32_16x16x32_bf16(af[t], bwq[tj], qa[t][tj], 0, 0, 0);
                    ka[t][tj] = __builtin_amdgcn_mfma_f32_16x16x32_bf16(af[t], bwk[tj], ka[t][tj], 0, 0, 0);
                    va[t][tj] = __builtin_amdgcn_mfma_f32_16x16x32_bf16(af[t], bwv[tj], va[t][tj], 0, 0, 0);
                }
            __builtin_amdgcn_s_setprio(0);
        }
        // +bias, write out (R12-verbatim formulas)
#pragma unroll
        for (int tj = 0; tj < 2; ++tj) {
            float bqv = b_all[hc + tj * 16 + lr];
            float bkr = b_all[256 + hc + tj * 16 + lr];
            float bvr = b_all[512 + hc + tj * 16 + lr];
#pragma unroll
            for (int t = 0; t < 2; ++t) {
#pragma unroll
                for (int e = 0; e < 4; ++e) {
                    int tok = hf * 32 + t * 16 + lg * 4 + e;
                    qb[tok * 32 + tj * 16 + lr]  = f2b(qa[t][tj][e] + bqv);
                    kb_[tok * 32 + tj * 16 + lr] = f2b(ka[t][tj][e] + bkr);
                }
                int dh   = tj * 16 + lr;
                int tok0 = hf * 32 + t * 16 + lg * 4;
                u32x2 pv2;
                pv2[0] = cvtpk(va[t][tj][0] + bvr, va[t][tj][1] + bvr);
                pv2[1] = cvtpk(va[t][tj][2] + bvr, va[t][tj][3] + bvr);
                *(u32x2*)(vb + dh * 128 + tok0 * 2) = pv2;
            }
        }
    }
}

// ================= Kernel B: attention + output projection =================
// R12-verbatim except wpt frag-major load.
__global__ __launch_bounds__(512, 4)
void attn_out(const u16* __restrict__ qkv,
              const float* __restrict__ mask,
              const u16* __restrict__ wpt,
              const float* __restrict__ bp,
              float* __restrict__ out)
{
    __shared__ __align__(16) unsigned char smem[40960];
    const int b   = blockIdx.x;
    const int wdw = b & 255;
    const int tid = threadIdx.x;
    const int w   = tid >> 6;
    const int l   = tid & 63;
    const int lr  = l & 15;
    const int lg  = l >> 4;
    const int chunk = w * 4096;
    const int moff  = 32768;
    const int hc    = w * 32;
    const float scale = 0.17677669529663687f;

    f32x4 zero = {0.f, 0.f, 0.f, 0.f};

    // ---------- mask -> LDS f16 permuted (R12-verbatim) ----------
    {
        const float* mb = mask + (size_t)wdw * 4096;
#pragma unroll
        for (int it = 0; it < 8; ++it) {
            int idx = it * 512 + tid;
            int q = idx >> 6, k = idx & 63;
            int colp = (k & 15) * 4 + (k >> 4);
            *(f16s*)(smem + moff + q * 128 + ((colp * 2) ^ ((q & 7) << 4)))
                = (_Float16)mb[idx];
        }
    }
    __syncthreads();   // #1

    const u16* qb  = qkv + (((size_t)b * 8 + w) * 3) * 2048;
    const u16* kb_ = qb + 2048;
    const unsigned char* vb = (const unsigned char*)(qb + 4096);

    bf16v8 aq[4], bk[4];
#pragma unroll
    for (int ti = 0; ti < 4; ++ti)
        aq[ti] = *(const bf16x8*)(qb + (ti * 16 + lr) * 32 + lg * 8);
#pragma unroll
    for (int tj = 0; tj < 4; ++tj)
        bk[tj] = *(const bf16x8*)(kb_ + (tj * 16 + lr) * 32 + lg * 8);

    // ---------- S = Q K^T + softmax (R12-verbatim) ----------
    f32x4 sH[4][4];
    __builtin_amdgcn_s_setprio(1);
#pragma unroll
    for (int ti = 0; ti < 4; ++ti)
#pragma unroll
        for (int tj = 0; tj < 4; ++tj)
            sH[ti][tj] = __builtin_amdgcn_mfma_f32_16x16x32_bf16(aq[ti], bk[tj], zero, 0, 0, 0);
    __builtin_amdgcn_s_setprio(0);

#pragma unroll
    for (int ti = 0; ti < 4; ++ti)
#pragma unroll
        for (int e = 0; e < 4; ++e) {
            int row = ti * 16 + lg * 4 + e;
            f16v4 mv = *(const f16x4*)(smem + moff + row * 128 + ((lr * 8) ^ ((row & 7) << 4)));
#pragma unroll
            for (int tj = 0; tj < 4; ++tj)
                sH[ti][tj][e] = sH[ti][tj][e] * scale + (float)mv[tj];
        }
    float inv[4][4];
#pragma unroll
    for (int ti = 0; ti < 4; ++ti)
#pragma unroll
        for (int e = 0; e < 4; ++e) {
            float v0 = sH[ti][0][e], v1 = sH[ti][1][e];
            float v2 = sH[ti][2][e], v3 = sH[ti][3][e];
            float m = fmaxf(fmaxf(v0, v1), fmaxf(v2, v3));
#pragma unroll
            for (int d = 1; d < 16; d <<= 1) m = fmaxf(m, __shfl_xor(m, d));
            v0 = __expf(v0 - m); v1 = __expf(v1 - m);
            v2 = __expf(v2 - m); v3 = __expf(v3 - m);
            float s = v0 + v1 + v2 + v3;
#pragma unroll
            for (int d = 1; d < 16; d <<= 1) s += __shfl_xor(s, d);
            inv[ti][e] = 1.0f / s;
            sH[ti][0][e] = v0; sH[ti][1][e] = v1;
            sH[ti][2][e] = v2; sH[ti][3][e] = v3;
        }
    u32 pkP[4][4][2];
#pragma unroll
    for (int ti = 0; ti < 4; ++ti)
#pragma unroll
        for (int tj = 0; tj < 4; ++tj) {
            pkP[ti][tj][0] = cvtpk(sH[ti][tj][0], sH[ti][tj][1]);
            pkP[ti][tj][1] = cvtpk(sH[ti][tj][2], sH[ti][tj][3]);
        }

    // ---------- PV in two k-halves (R12-verbatim) ----------
    f32x4 oH[4][2];
#pragma unroll
    for (int ti = 0; ti < 4; ++ti)
#pragma unroll
        for (int tjv = 0; tjv < 2; ++tjv) oH[ti][tjv] = zero;
#pragma unroll
    for (int kb2 = 0; kb2 < 2; ++kb2) {
#pragma unroll
        for (int ti = 0; ti < 4; ++ti)
#pragma unroll
            for (int tjh = 0; tjh < 2; ++tjh) {
                int c2 = (tjh * 16 + lr) * 2;
#pragma unroll
                for (int ep = 0; ep < 2; ++ep) {
                    u32 u = pkP[ti][2 * kb2 + tjh][ep];
                    int q0 = ti * 16 + lg * 4 + ep * 2;
                    *(u16*)(smem + chunk + q0 * 64 + (c2 ^ (((q0 >> 1) & 3) << 4))) = (unsigned short)u;
                    *(u16*)(smem + chunk + (q0 + 1) * 64 + (c2 ^ ((((q0 + 1) >> 1) & 3) << 4))) = (unsigned short)(u >> 16);
                }
            }
        MEMFENCE();
        bf16v8 bv[2];
#pragma unroll
        for (int tjv = 0; tjv < 2; ++tjv) {
            int dh = tjv * 16 + lr;
            bv[tjv] = *(const bf16x8*)(vb + dh * 128 + kb2 * 64 + lg * 16);
        }
#pragma unroll
        for (int ti = 0; ti < 4; ++ti) {
            int row = ti * 16 + lr;
            bf16v8 ap = *(const bf16x8*)(smem + chunk + row * 64 + ((lg * 16) ^ (((row >> 1) & 3) << 4)));
            __builtin_amdgcn_s_setprio(1);
#pragma unroll
            for (int tjv = 0; tjv < 2; ++tjv)
                oH[ti][tjv] = __builtin_amdgcn_mfma_f32_16x16x32_bf16(ap, bv[tjv], oH[ti][tjv], 0, 0, 0);
            __builtin_amdgcn_s_setprio(0);
        }
        MEMFENCE();
    }
#pragma unroll
    for (int ti = 0; ti < 4; ++ti)
#pragma unroll
        for (int tjv = 0; tjv < 2; ++tjv)
#pragma unroll
            for (int e = 0; e < 4; ++e)
                oH[ti][tjv][e] *= inv[ti][e];

    __syncthreads();   // #2

    // ---------- stage O -> O_lds[64][256] (R12-verbatim) ----------
#pragma unroll
    for (int ti = 0; ti < 4; ++ti)
#pragma unroll
        for (int tjv = 0; tjv < 2; ++tjv)
#pragma unroll
            for (int e = 0; e < 4; ++e) {
                int row = ti * 16 + lg * 4 + e;
                int cg  = hc + tjv * 16 + lr;
                *(u16*)(smem + row * 512 + ((cg * 2) ^ ((row & 7) << 4)))
                    = f2b(oH[ti][tjv][e]);
            }
    __syncthreads();   // #3

    // ---------- output projection (frag-major wpt) ----------
    f32x4 pacc[4][2];
#pragma unroll
    for (int ti = 0; ti < 4; ++ti)
#pragma unroll
        for (int tj = 0; tj < 2; ++tj) pacc[ti][tj] = zero;
#pragma unroll
    for (int ks = 0; ks < 8; ++ks) {
        bf16v8 a_[4];
#pragma unroll
        for (int ti = 0; ti < 4; ++ti) {
            int row = ti * 16 + lr;
            a_[ti] = *(const bf16x8*)(smem + row * 512 + ((ks * 64 + lg * 16) ^ ((row & 7) << 4)));
        }
        bf16v8 bw[2];
#pragma unroll
        for (int tj = 0; tj < 2; ++tj)
            bw[tj] = *(const bf16x8*)(wpt + (size_t)w * 8192 + tj * 4096 + ks * 512 + l * 8);
        __builtin_amdgcn_s_setprio(1);
#pragma unroll
        for (int tj = 0; tj < 2; ++tj)
#pragma unroll
            for (int ti = 0; ti < 4; ++ti)
                pacc[ti][tj] = __builtin_amdgcn_mfma_f32_16x16x32_bf16(a_[ti], bw[tj], pacc[ti][tj], 0, 0, 0);
        __builtin_amdgcn_s_setprio(0);
    }
    float* ob = out + (size_t)b * 16384;
#pragma unroll
    for (int tj = 0; tj < 2; ++tj) {
        float bias = bp[hc + tj * 16 + lr];
#pragma unroll
        for (int ti = 0; ti < 4; ++ti)
#pragma unroll
            for (int e = 0; e < 4; ++e) {
                int row = ti * 16 + lg * 4 + e;
                ob[row * 256 + hc + tj * 16 + lr] = pacc[ti][tj][e] + bias;
            }
    }
}

extern "C" void kernel_launch(void* const* d_in, const int* in_sizes, int n_in,
                              void* d_out, int out_size, void* d_ws, size_t ws_size,
                              hipStream_t stream) {
    const float* x    = (const float*)d_in[0];
    const float* mask = (const float*)d_in[1];
    const float* Wq   = (const float*)d_in[2];
    const float* bq   = (const float*)d_in[3];
    const float* Wkv  = (const float*)d_in[4];
    const float* bkv  = (const float*)d_in[5];
    const float* Wp   = (const float*)d_in[6];
    const float* bp   = (const float*)d_in[7];
    float* out = (float*)d_out;

    u16*   wt    = (u16*)d_ws;                    // 196608 u16 (frag-major)
    u16*   wpt   = wt + 196608;                   // 65536 u16 (frag-major)
    float* b_all = (float*)(wpt + 65536);         // 768 f32

    const size_t qkv_off   = 589824;              // bytes
    u16* qkv = (u16*)((unsigned char*)d_ws + qkv_off);

    prep_weights<<<1027, 256, 0, stream>>>(Wq, Wkv, Wp, bq, bkv, wt, wpt, b_all);
    qkv_proj<<<2048, 512, 0, stream>>>(x, wt, b_all, qkv);
    attn_out<<<2048, 512, 0, stream>>>(qkv, mask, wpt, bp, out);
}

// Round 14
// 226.182 us; speedup vs baseline: 1.4918x; 1.0127x over previous
//
#include <hip/hip_runtime.h>

// may_alias types for all LDS/global reinterpret accesses
typedef __bf16 bf16v8 __attribute__((ext_vector_type(8)));
typedef bf16v8 bf16x8 __attribute__((may_alias));
typedef unsigned int u32v2 __attribute__((ext_vector_type(2)));
typedef u32v2 u32x2 __attribute__((may_alias));
typedef unsigned short u16v8 __attribute__((ext_vector_type(8)));
typedef u16v8 u16x8 __attribute__((may_alias));
typedef unsigned short u16v;
typedef u16v u16 __attribute__((may_alias));
typedef _Float16 f16v4 __attribute__((ext_vector_type(4)));
typedef f16v4 f16x4 __attribute__((may_alias));
typedef _Float16 f16v;
typedef f16v f16s __attribute__((may_alias));
typedef float f32x4 __attribute__((ext_vector_type(4)));
typedef unsigned int u32;

#define MEMFENCE() asm volatile("" ::: "memory")

union B8 { u32 u[4]; bf16v8 v; };

__device__ __forceinline__ u32 cvtpk(float lo, float hi) {
    u32 r;
    asm("v_cvt_pk_bf16_f32 %0, %1, %2" : "=v"(r) : "v"(lo), "v"(hi));
    return r;
}

__device__ __forceinline__ unsigned short f2b(float f) {
    union { float f; unsigned u; } a; a.f = f;
    unsigned r = a.u + 0x7FFFu + ((a.u >> 16) & 1u);   // RNE
    return (unsigned short)(r >> 16);
}

// ---- weight prep: FRAGMENT-MAJOR layouts (R13-verbatim) ----
// wt  [h][m][tj][ks][lane][j]  (196608 u16): W^T[o=h*32+tj*16+(lane&15)][k=ks*32+(lane>>4)*8+j]
// wpt [h][tj][ks][lane][j]     (65536 u16):  same with Wp
__global__ void prep_weights(const float* __restrict__ Wq,
                             const float* __restrict__ Wkv,
                             const float* __restrict__ Wp,
                             const float* __restrict__ bq,
                             const float* __restrict__ bkv,
                             u16* __restrict__ wt,
                             u16* __restrict__ wpt,
                             float* __restrict__ b_all)
{
    int idx = blockIdx.x * 256 + threadIdx.x;
    if (idx < 196608) {
        int h  = idx / 24576;   int r  = idx % 24576;
        int m  = r / 8192;      int r2 = r % 8192;
        int tj = r2 / 4096;     int r3 = r2 % 4096;
        int ks = r3 / 512;      int r4 = r3 % 512;
        int lane = r4 >> 3, j = r4 & 7;
        int o = h * 32 + tj * 16 + (lane & 15);
        int k = ks * 32 + (lane >> 4) * 8 + j;
        float v = (m == 0) ? Wq[k * 256 + o]
                           : Wkv[k * 512 + (m == 1 ? o : 256 + o)];
        wt[idx] = f2b(v);
    } else if (idx < 262144) {
        int f  = idx - 196608;
        int h  = f / 8192;      int r2 = f % 8192;
        int tj = r2 / 4096;     int r3 = r2 % 4096;
        int ks = r3 / 512;      int r4 = r3 % 512;
        int lane = r4 >> 3, j = r4 & 7;
        int o = h * 32 + tj * 16 + (lane & 15);
        int k = ks * 32 + (lane >> 4) * 8 + j;
        wpt[f] = f2b(Wp[k * 256 + o]);
    } else if (idx < 262912) {
        int i = idx - 262144;
        b_all[i] = (i < 256) ? bq[i] : bkv[i - 256];
    }
}

// ================= Kernel A: QKV projection — 3-pass low-register variant =========
// R13 deltas: Q/K/V computed in SEPARATE passes per hf (acc 16 + weights 16 + af 16
// ≈ 58 live regs, no K/V parking) -> fits the 64-VGPR tier; __launch_bounds__(512,4)
// -> up to 4 blocks/CU so TLP hides the per-iter L2 weight-load latency. Each pass
// streams a contiguous 16KB frag-major weight region (L1-resident on 2nd hf).
// All store formulas R13-byte-identical.
__global__ __launch_bounds__(512, 4)
void qkv_proj(const float* __restrict__ x,
              const u16* __restrict__ wt,
              const float* __restrict__ b_all,
              u16* __restrict__ qkv)
{
    __shared__ __align__(16) unsigned char smem[32768];
    const int b   = blockIdx.x;
    const int tid = threadIdx.x;
    const int w   = tid >> 6;
    const int l   = tid & 63;
    const int lr  = l & 15;
    const int lg  = l >> 4;
    const int hc  = w * 32;

    f32x4 zero = {0.f, 0.f, 0.f, 0.f};

    // ---------- stage x -> xs bf16 (R13-verbatim) ----------
    {
        const float* xb = x + (size_t)b * 16384;
#pragma unroll
        for (int it = 0; it < 4; ++it) {
            int g   = it * 512 + tid;
            int row = g >> 5;
            int cg  = g & 31;
            const float4 f0 = *(const float4*)(xb + row * 256 + cg * 8);
            const float4 f1 = *(const float4*)(xb + row * 256 + cg * 8 + 4);
            u16v8 t;
            t[0] = f2b(f0.x); t[1] = f2b(f0.y); t[2] = f2b(f0.z); t[3] = f2b(f0.w);
            t[4] = f2b(f1.x); t[5] = f2b(f1.y); t[6] = f2b(f1.z); t[7] = f2b(f1.w);
            int off = row * 512 + ((cg * 16) ^ ((row & 7) << 4));
            *(u16x8*)(smem + off) = t;
        }
    }
    __syncthreads();

    u16* qb  = qkv + (((size_t)b * 8 + w) * 3) * 2048;
    u16* kb_ = qb + 2048;
    unsigned char* vb = (unsigned char*)(qb + 4096);
    const u16* whead = wt + (size_t)w * 24576;   // per-head frag block

#pragma unroll
    for (int hf = 0; hf < 2; ++hf) {
        // ---------------- Q pass ----------------
        {
            f32x4 acc[2][2];
#pragma unroll
            for (int t = 0; t < 2; ++t)
#pragma unroll
                for (int tj = 0; tj < 2; ++tj) acc[t][tj] = zero;
#pragma unroll
            for (int ks = 0; ks < 8; ++ks) {
                bf16v8 af[2];
#pragma unroll
                for (int t = 0; t < 2; ++t) {
                    int row = hf * 32 + t * 16 + lr;
                    af[t] = *(const bf16x8*)(smem + row * 512 + ((ks * 64 + lg * 16) ^ ((row & 7) << 4)));
                }
                bf16v8 wq[2];
#pragma unroll
                for (int tj = 0; tj < 2; ++tj)
                    wq[tj] = *(const bf16x8*)(whead + tj * 4096 + ks * 512 + l * 8);
                __builtin_amdgcn_s_setprio(1);
#pragma unroll
                for (int tj = 0; tj < 2; ++tj)
#pragma unroll
                    for (int t = 0; t < 2; ++t)
                        acc[t][tj] = __builtin_amdgcn_mfma_f32_16x16x32_bf16(af[t], wq[tj], acc[t][tj], 0, 0, 0);
                __builtin_amdgcn_s_setprio(0);
            }
#pragma unroll
            for (int tj = 0; tj < 2; ++tj) {
                float bqv = b_all[hc + tj * 16 + lr];
#pragma unroll
                for (int t = 0; t < 2; ++t)
#pragma unroll
                    for (int e = 0; e < 4; ++e) {
                        int tok = hf * 32 + t * 16 + lg * 4 + e;
                        qb[tok * 32 + tj * 16 + lr] = f2b(acc[t][tj][e] + bqv);
                    }
            }
        }
        // ---------------- K pass ----------------
        {
            f32x4 acc[2][2];
#pragma unroll
            for (int t = 0; t < 2; ++t)
#pragma unroll
                for (int tj = 0; tj < 2; ++tj) acc[t][tj] = zero;
#pragma unroll
            for (int ks = 0; ks < 8; ++ks) {
                bf16v8 af[2];
#pragma unroll
                for (int t = 0; t < 2; ++t) {
                    int row = hf * 32 + t * 16 + lr;
                    af[t] = *(const bf16x8*)(smem + row * 512 + ((ks * 64 + lg * 16) ^ ((row & 7) << 4)));
                }
                bf16v8 wk[2];
#pragma unroll
                for (int tj = 0; tj < 2; ++tj)
                    wk[tj] = *(const bf16x8*)(whead + 8192 + tj * 4096 + ks * 512 + l * 8);
                __builtin_amdgcn_s_setprio(1);
#pragma unroll
                for (int tj = 0; tj < 2; ++tj)
#pragma unroll
                    for (int t = 0; t < 2; ++t)
                        acc[t][tj] = __builtin_amdgcn_mfma_f32_16x16x32_bf16(af[t], wk[tj], acc[t][tj], 0, 0, 0);
                __builtin_amdgcn_s_setprio(0);
            }
#pragma unroll
            for (int tj = 0; tj < 2; ++tj) {
                float bkr = b_all[256 + hc + tj * 16 + lr];
#pragma unroll
                for (int t = 0; t < 2; ++t)
#pragma unroll
                    for (int e = 0; e < 4; ++e) {
                        int tok = hf * 32 + t * 16 + lg * 4 + e;
                        kb_[tok * 32 + tj * 16 + lr] = f2b(acc[t][tj][e] + bkr);
                    }
            }
        }
        // ---------------- V pass (packed V^T store) ----------------
        {
            f32x4 acc[2][2];
#pragma unroll
            for (int t = 0; t < 2; ++t)
#pragma unroll
                for (int tj = 0; tj < 2; ++tj) acc[t][tj] = zero;
#pragma unroll
            for (int ks = 0; ks < 8; ++ks) {
                bf16v8 af[2];
#pragma unroll
                for (int t = 0; t < 2; ++t) {
                    int row = hf * 32 + t * 16 + lr;
                    af[t] = *(const bf16x8*)(smem + row * 512 + ((ks * 64 + lg * 16) ^ ((row & 7) << 4)));
                }
                bf16v8 wv[2];
#pragma unroll
                for (int tj = 0; tj < 2; ++tj)
                    wv[tj] = *(const bf16x8*)(whead + 16384 + tj * 4096 + ks * 512 + l * 8);
                __builtin_amdgcn_s_setprio(1);
#pragma unroll
                for (int tj = 0; tj < 2; ++tj)
#pragma unroll
                    for (int t = 0; t < 2; ++t)
                        acc[t][tj] = __builtin_amdgcn_mfma_f32_16x16x32_bf16(af[t], wv[tj], acc[t][tj], 0, 0, 0);
                __builtin_amdgcn_s_setprio(0);
            }
#pragma unroll
            for (int tj = 0; tj < 2; ++tj) {
                float bvr = b_all[512 + hc + tj * 16 + lr];
#pragma unroll
                for (int t = 0; t < 2; ++t) {
                    int dh   = tj * 16 + lr;
                    int tok0 = hf * 32 + t * 16 + lg * 4;
                    u32x2 pv2;
                    pv2[0] = cvtpk(acc[t][tj][0] + bvr, acc[t][tj][1] + bvr);
                    pv2[1] = cvtpk(acc[t][tj][2] + bvr, acc[t][tj][3] + bvr);
                    *(u32x2*)(vb + dh * 128 + tok0 * 2) = pv2;
                }
            }
        }
    }
}

// ================= Kernel B: attention + output projection (R13-verbatim) =========
__global__ __launch_bounds__(512, 4)
void attn_out(const u16* __restrict__ qkv,
              const float* __restrict__ mask,
              const u16* __restrict__ wpt,
              const float* __restrict__ bp,
              float* __restrict__ out)
{
    __shared__ __align__(16) unsigned char smem[40960];
    const int b   = blockIdx.x;
    const int wdw = b & 255;
    const int tid = threadIdx.x;
    const int w   = tid >> 6;
    const int l   = tid & 63;
    const int lr  = l & 15;
    const int lg  = l >> 4;
    const int chunk = w * 4096;
    const int moff  = 32768;
    const int hc    = w * 32;
    const float scale = 0.17677669529663687f;

    f32x4 zero = {0.f, 0.f, 0.f, 0.f};

    // ---------- mask -> LDS f16 permuted ----------
    {
        const float* mb = mask + (size_t)wdw * 4096;
#pragma unroll
        for (int it = 0; it < 8; ++it) {
            int idx = it * 512 + tid;
            int q = idx >> 6, k = idx & 63;
            int colp = (k & 15) * 4 + (k >> 4);
            *(f16s*)(smem + moff + q * 128 + ((colp * 2) ^ ((q & 7) << 4)))
                = (_Float16)mb[idx];
        }
    }
    __syncthreads();   // #1

    const u16* qb  = qkv + (((size_t)b * 8 + w) * 3) * 2048;
    const u16* kb_ = qb + 2048;
    const unsigned char* vb = (const unsigned char*)(qb + 4096);

    bf16v8 aq[4], bk[4];
#pragma unroll
    for (int ti = 0; ti < 4; ++ti)
        aq[ti] = *(const bf16x8*)(qb + (ti * 16 + lr) * 32 + lg * 8);
#pragma unroll
    for (int tj = 0; tj < 4; ++tj)
        bk[tj] = *(const bf16x8*)(kb_ + (tj * 16 + lr) * 32 + lg * 8);

    // ---------- S = Q K^T + softmax ----------
    f32x4 sH[4][4];
    __builtin_amdgcn_s_setprio(1);
#pragma unroll
    for (int ti = 0; ti < 4; ++ti)
#pragma unroll
        for (int tj = 0; tj < 4; ++tj)
            sH[ti][tj] = __builtin_amdgcn_mfma_f32_16x16x32_bf16(aq[ti], bk[tj], zero, 0, 0, 0);
    __builtin_amdgcn_s_setprio(0);

#pragma unroll
    for (int ti = 0; ti < 4; ++ti)
#pragma unroll
        for (int e = 0; e < 4; ++e) {
            int row = ti * 16 + lg * 4 + e;
            f16v4 mv = *(const f16x4*)(smem + moff + row * 128 + ((lr * 8) ^ ((row & 7) << 4)));
#pragma unroll
            for (int tj = 0; tj < 4; ++tj)
                sH[ti][tj][e] = sH[ti][tj][e] * scale + (float)mv[tj];
        }
    float inv[4][4];
#pragma unroll
    for (int ti = 0; ti < 4; ++ti)
#pragma unroll
        for (int e = 0; e < 4; ++e) {
            float v0 = sH[ti][0][e], v1 = sH[ti][1][e];
            float v2 = sH[ti][2][e], v3 = sH[ti][3][e];
            float m = fmaxf(fmaxf(v0, v1), fmaxf(v2, v3));
#pragma unroll
            for (int d = 1; d < 16; d <<= 1) m = fmaxf(m, __shfl_xor(m, d));
            v0 = __expf(v0 - m); v1 = __expf(v1 - m);
            v2 = __expf(v2 - m); v3 = __expf(v3 - m);
            float s = v0 + v1 + v2 + v3;
#pragma unroll
            for (int d = 1; d < 16; d <<= 1) s += __shfl_xor(s, d);
            inv[ti][e] = 1.0f / s;
            sH[ti][0][e] = v0; sH[ti][1][e] = v1;
            sH[ti][2][e] = v2; sH[ti][3][e] = v3;
        }
    u32 pkP[4][4][2];
#pragma unroll
    for (int ti = 0; ti < 4; ++ti)
#pragma unroll
        for (int tj = 0; tj < 4; ++tj) {
            pkP[ti][tj][0] = cvtpk(sH[ti][tj][0], sH[ti][tj][1]);
            pkP[ti][tj][1] = cvtpk(sH[ti][tj][2], sH[ti][tj][3]);
        }

    // ---------- PV in two k-halves ----------
    f32x4 oH[4][2];
#pragma unroll
    for (int ti = 0; ti < 4; ++ti)
#pragma unroll
        for (int tjv = 0; tjv < 2; ++tjv) oH[ti][tjv] = zero;
#pragma unroll
    for (int kb2 = 0; kb2 < 2; ++kb2) {
#pragma unroll
        for (int ti = 0; ti < 4; ++ti)
#pragma unroll
            for (int tjh = 0; tjh < 2; ++tjh) {
                int c2 = (tjh * 16 + lr) * 2;
#pragma unroll
                for (int ep = 0; ep < 2; ++ep) {
                    u32 u = pkP[ti][2 * kb2 + tjh][ep];
                    int q0 = ti * 16 + lg * 4 + ep * 2;
                    *(u16*)(smem + chunk + q0 * 64 + (c2 ^ (((q0 >> 1) & 3) << 4))) = (unsigned short)u;
                    *(u16*)(smem + chunk + (q0 + 1) * 64 + (c2 ^ ((((q0 + 1) >> 1) & 3) << 4))) = (unsigned short)(u >> 16);
                }
            }
        MEMFENCE();
        bf16v8 bv[2];
#pragma unroll
        for (int tjv = 0; tjv < 2; ++tjv) {
            int dh = tjv * 16 + lr;
            bv[tjv] = *(const bf16x8*)(vb + dh * 128 + kb2 * 64 + lg * 16);
        }
#pragma unroll
        for (int ti = 0; ti < 4; ++ti) {
            int row = ti * 16 + lr;
            bf16v8 ap = *(const bf16x8*)(smem + chunk + row * 64 + ((lg * 16) ^ (((row >> 1) & 3) << 4)));
            __builtin_amdgcn_s_setprio(1);
#pragma unroll
            for (int tjv = 0; tjv < 2; ++tjv)
                oH[ti][tjv] = __builtin_amdgcn_mfma_f32_16x16x32_bf16(ap, bv[tjv], oH[ti][tjv], 0, 0, 0);
            __builtin_amdgcn_s_setprio(0);
        }
        MEMFENCE();
    }
#pragma unroll
    for (int ti = 0; ti < 4; ++ti)
#pragma unroll
        for (int tjv = 0; tjv < 2; ++tjv)
#pragma unroll
            for (int e = 0; e < 4; ++e)
                oH[ti][tjv][e] *= inv[ti][e];

    __syncthreads();   // #2

    // ---------- stage O -> O_lds[64][256] ----------
#pragma unroll
    for (int ti = 0; ti < 4; ++ti)
#pragma unroll
        for (int tjv = 0; tjv < 2; ++tjv)
#pragma unroll
            for (int e = 0; e < 4; ++e) {
                int row = ti * 16 + lg * 4 + e;
                int cg  = hc + tjv * 16 + lr;
                *(u16*)(smem + row * 512 + ((cg * 2) ^ ((row & 7) << 4)))
                    = f2b(oH[ti][tjv][e]);
            }
    __syncthreads();   // #3

    // ---------- output projection (frag-major wpt) ----------
    f32x4 pacc[4][2];
#pragma unroll
    for (int ti = 0; ti < 4; ++ti)
#pragma unroll
        for (int tj = 0; tj < 2; ++tj) pacc[ti][tj] = zero;
#pragma unroll
    for (int ks = 0; ks < 8; ++ks) {
        bf16v8 a_[4];
#pragma unroll
        for (int ti = 0; ti < 4; ++ti) {
            int row = ti * 16 + lr;
            a_[ti] = *(const bf16x8*)(smem + row * 512 + ((ks * 64 + lg * 16) ^ ((row & 7) << 4)));
        }
        bf16v8 bw[2];
#pragma unroll
        for (int tj = 0; tj < 2; ++tj)
            bw[tj] = *(const bf16x8*)(wpt + (size_t)w * 8192 + tj * 4096 + ks * 512 + l * 8);
        __builtin_amdgcn_s_setprio(1);
#pragma unroll
        for (int tj = 0; tj < 2; ++tj)
#pragma unroll
            for (int ti = 0; ti < 4; ++ti)
                pacc[ti][tj] = __builtin_amdgcn_mfma_f32_16x16x32_bf16(a_[ti], bw[tj], pacc[ti][tj], 0, 0, 0);
        __builtin_amdgcn_s_setprio(0);
    }
    float* ob = out + (size_t)b * 16384;
#pragma unroll
    for (int tj = 0; tj < 2; ++tj) {
        float bias = bp[hc + tj * 16 + lr];
#pragma unroll
        for (int ti = 0; ti < 4; ++ti)
#pragma unroll
            for (int e = 0; e < 4; ++e) {
                int row = ti * 16 + lg * 4 + e;
                ob[row * 256 + hc + tj * 16 + lr] = pacc[ti][tj][e] + bias;
            }
    }
}

extern "C" void kernel_launch(void* const* d_in, const int* in_sizes, int n_in,
                              void* d_out, int out_size, void* d_ws, size_t ws_size,
                              hipStream_t stream) {
    const float* x    = (const float*)d_in[0];
    const float* mask = (const float*)d_in[1];
    const float* Wq   = (const float*)d_in[2];
    const float* bq   = (const float*)d_in[3];
    const float* Wkv  = (const float*)d_in[4];
    const float* bkv  = (const float*)d_in[5];
    const float* Wp   = (const float*)d_in[6];
    const float* bp   = (const float*)d_in[7];
    float* out = (float*)d_out;

    u16*   wt    = (u16*)d_ws;                    // 196608 u16 (frag-major)
    u16*   wpt   = wt + 196608;                   // 65536 u16 (frag-major)
    float* b_all = (float*)(wpt + 65536);         // 768 f32

    const size_t qkv_off   = 589824;              // bytes
    u16* qkv = (u16*)((unsigned char*)d_ws + qkv_off);

    prep_weights<<<1027, 256, 0, stream>>>(Wq, Wkv, Wp, bq, bkv, wt, wpt, b_all);
    qkv_proj<<<2048, 512, 0, stream>>>(x, wt, b_all, qkv);
    attn_out<<<2048, 512, 0, stream>>>(qkv, mask, wpt, bp, out);
}

// Round 15
// 202.640 us; speedup vs baseline: 1.6651x; 1.1162x over previous
//
#include <hip/hip_runtime.h>

// may_alias types for all LDS/global reinterpret accesses
typedef __bf16 bf16v8 __attribute__((ext_vector_type(8)));
typedef bf16v8 bf16x8 __attribute__((may_alias));
typedef unsigned int u32v2 __attribute__((ext_vector_type(2)));
typedef u32v2 u32x2 __attribute__((may_alias));
typedef unsigned short u16v8 __attribute__((ext_vector_type(8)));
typedef u16v8 u16x8 __attribute__((may_alias));
typedef unsigned short u16v;
typedef u16v u16 __attribute__((may_alias));
typedef _Float16 f16v4 __attribute__((ext_vector_type(4)));
typedef f16v4 f16x4 __attribute__((may_alias));
typedef _Float16 f16v;
typedef f16v f16s __attribute__((may_alias));
typedef float f32x4 __attribute__((ext_vector_type(4)));
typedef unsigned int u32;

#define MEMFENCE() asm volatile("" ::: "memory")

union B8 { u32 u[4]; bf16v8 v; };

__device__ __forceinline__ u32 cvtpk(float lo, float hi) {
    u32 r;
    asm("v_cvt_pk_bf16_f32 %0, %1, %2" : "=v"(r) : "v"(lo), "v"(hi));
    return r;
}

__device__ __forceinline__ unsigned short f2b(float f) {
    union { float f; unsigned u; } a; a.f = f;
    unsigned r = a.u + 0x7FFFu + ((a.u >> 16) & 1u);   // RNE
    return (unsigned short)(r >> 16);
}

// ---- weight prep: FRAGMENT-MAJOR layouts (R13-verbatim) ----
// wt  [h][m][tj][ks][lane][j]  (196608 u16): W^T[o=h*32+tj*16+(lane&15)][k=ks*32+(lane>>4)*8+j]
// wpt [h][tj][ks][lane][j]     (65536 u16):  same with Wp
__global__ void prep_weights(const float* __restrict__ Wq,
                             const float* __restrict__ Wkv,
                             const float* __restrict__ Wp,
                             const float* __restrict__ bq,
                             const float* __restrict__ bkv,
                             u16* __restrict__ wt,
                             u16* __restrict__ wpt,
                             float* __restrict__ b_all)
{
    int idx = blockIdx.x * 256 + threadIdx.x;
    if (idx < 196608) {
        int h  = idx / 24576;   int r  = idx % 24576;
        int m  = r / 8192;      int r2 = r % 8192;
        int tj = r2 / 4096;     int r3 = r2 % 4096;
        int ks = r3 / 512;      int r4 = r3 % 512;
        int lane = r4 >> 3, j = r4 & 7;
        int o = h * 32 + tj * 16 + (lane & 15);
        int k = ks * 32 + (lane >> 4) * 8 + j;
        float v = (m == 0) ? Wq[k * 256 + o]
                           : Wkv[k * 512 + (m == 1 ? o : 256 + o)];
        wt[idx] = f2b(v);
    } else if (idx < 262144) {
        int f  = idx - 196608;
        int h  = f / 8192;      int r2 = f % 8192;
        int tj = r2 / 4096;     int r3 = r2 % 4096;
        int ks = r3 / 512;      int r4 = r3 % 512;
        int lane = r4 >> 3, j = r4 & 7;
        int o = h * 32 + tj * 16 + (lane & 15);
        int k = ks * 32 + (lane >> 4) * 8 + j;
        wpt[f] = f2b(Wp[k * 256 + o]);
    } else if (idx < 262912) {
        int i = idx - 262144;
        b_all[i] = (i < 256) ? bq[i] : bkv[i - 256];
    }
}

// ================= Kernel A: QKV projection — 2 windows/block (R15) =================
// Each weight fragment now feeds 4 MFMAs (2 windows x 2 token-tiles) -> per-dispatch
// L2 weight traffic halves (1.57GB -> 0.78GB), attacking the measured L2-transaction
// bound. xs = 2 windows x 32KB = 64KB LDS -> still 2 blocks/CU. Per-pass live regs
// ~80 -> (512,2) = 128-VGPR tier (R11-proven), no spill. All formulas R14-verbatim
// modulo window offset.
__global__ __launch_bounds__(512, 2)
void qkv_proj(const float* __restrict__ x,
              const u16* __restrict__ wt,
              const float* __restrict__ b_all,
              u16* __restrict__ qkv)
{
    __shared__ __align__(16) unsigned char smem[65536];
    const int b0  = blockIdx.x * 2;
    const int tid = threadIdx.x;
    const int w   = tid >> 6;
    const int l   = tid & 63;
    const int lr  = l & 15;
    const int lg  = l >> 4;
    const int hc  = w * 32;

    f32x4 zero = {0.f, 0.f, 0.f, 0.f};

    // ---------- stage 2 windows of x -> xs bf16 (R14 formula + win offset) ----------
#pragma unroll
    for (int it = 0; it < 8; ++it) {
        int g   = it * 512 + tid;          // 0..4095 8-float groups
        int win = g >> 11;
        int r2  = g & 2047;
        int row = r2 >> 5;
        int cg  = r2 & 31;
        const float* xb = x + (size_t)(b0 + win) * 16384;
        const float4 f0 = *(const float4*)(xb + row * 256 + cg * 8);
        const float4 f1 = *(const float4*)(xb + row * 256 + cg * 8 + 4);
        u16v8 t;
        t[0] = f2b(f0.x); t[1] = f2b(f0.y); t[2] = f2b(f0.z); t[3] = f2b(f0.w);
        t[4] = f2b(f1.x); t[5] = f2b(f1.y); t[6] = f2b(f1.z); t[7] = f2b(f1.w);
        int off = win * 32768 + row * 512 + ((cg * 16) ^ ((row & 7) << 4));
        *(u16x8*)(smem + off) = t;
    }
    __syncthreads();

    const u16* whead = wt + (size_t)w * 24576;   // per-head frag block

#pragma unroll
    for (int hf = 0; hf < 2; ++hf) {
#pragma unroll
        for (int m = 0; m < 3; ++m) {            // 0=Q, 1=K, 2=V
            f32x4 acc[2][2][2];                  // [win][t][tj]
#pragma unroll
            for (int win = 0; win < 2; ++win)
#pragma unroll
                for (int t = 0; t < 2; ++t)
#pragma unroll
                    for (int tj = 0; tj < 2; ++tj) acc[win][t][tj] = zero;
#pragma unroll
            for (int ks = 0; ks < 8; ++ks) {
                bf16v8 wf[2];
#pragma unroll
                for (int tj = 0; tj < 2; ++tj)
                    wf[tj] = *(const bf16x8*)(whead + m * 8192 + tj * 4096 + ks * 512 + l * 8);
#pragma unroll
                for (int win = 0; win < 2; ++win)
#pragma unroll
                    for (int t = 0; t < 2; ++t) {
                        int row = hf * 32 + t * 16 + lr;
                        bf16v8 af = *(const bf16x8*)(smem + win * 32768 + row * 512 +
                                                     ((ks * 64 + lg * 16) ^ ((row & 7) << 4)));
                        __builtin_amdgcn_s_setprio(1);
#pragma unroll
                        for (int tj = 0; tj < 2; ++tj)
                            acc[win][t][tj] = __builtin_amdgcn_mfma_f32_16x16x32_bf16(af, wf[tj], acc[win][t][tj], 0, 0, 0);
                        __builtin_amdgcn_s_setprio(0);
                    }
            }
            // +bias, write out (R14-byte-identical formulas, + win offset)
#pragma unroll
            for (int win = 0; win < 2; ++win) {
                u16* base = qkv + (((size_t)(b0 + win) * 8 + w) * 3) * 2048 + m * 2048;
#pragma unroll
                for (int tj = 0; tj < 2; ++tj) {
                    float bias = b_all[m * 256 + hc + tj * 16 + lr];
#pragma unroll
                    for (int t = 0; t < 2; ++t) {
                        if (m < 2) {
#pragma unroll
                            for (int e = 0; e < 4; ++e) {
                                int tok = hf * 32 + t * 16 + lg * 4 + e;
                                base[tok * 32 + tj * 16 + lr] = f2b(acc[win][t][tj][e] + bias);
                            }
                        } else {
                            int dh   = tj * 16 + lr;
                            int tok0 = hf * 32 + t * 16 + lg * 4;
                            u32x2 pv2;
                            pv2[0] = cvtpk(acc[win][t][tj][0] + bias, acc[win][t][tj][1] + bias);
                            pv2[1] = cvtpk(acc[win][t][tj][2] + bias, acc[win][t][tj][3] + bias);
                            *(u32x2*)((unsigned char*)base + dh * 128 + tok0 * 2) = pv2;
                        }
                    }
                }
            }
        }
    }
}

// ================= Kernel B: attention + output projection (R13-verbatim) =========
__global__ __launch_bounds__(512, 4)
void attn_out(const u16* __restrict__ qkv,
              const float* __restrict__ mask,
              const u16* __restrict__ wpt,
              const float* __restrict__ bp,
              float* __restrict__ out)
{
    __shared__ __align__(16) unsigned char smem[40960];
    const int b   = blockIdx.x;
    const int wdw = b & 255;
    const int tid = threadIdx.x;
    const int w   = tid >> 6;
    const int l   = tid & 63;
    const int lr  = l & 15;
    const int lg  = l >> 4;
    const int chunk = w * 4096;
    const int moff  = 32768;
    const int hc    = w * 32;
    const float scale = 0.17677669529663687f;

    f32x4 zero = {0.f, 0.f, 0.f, 0.f};

    // ---------- mask -> LDS f16 permuted ----------
    {
        const float* mb = mask + (size_t)wdw * 4096;
#pragma unroll
        for (int it = 0; it < 8; ++it) {
            int idx = it * 512 + tid;
            int q = idx >> 6, k = idx & 63;
            int colp = (k & 15) * 4 + (k >> 4);
            *(f16s*)(smem + moff + q * 128 + ((colp * 2) ^ ((q & 7) << 4)))
                = (_Float16)mb[idx];
        }
    }
    __syncthreads();   // #1

    const u16* qb  = qkv + (((size_t)b * 8 + w) * 3) * 2048;
    const u16* kb_ = qb + 2048;
    const unsigned char* vb = (const unsigned char*)(qb + 4096);

    bf16v8 aq[4], bk[4];
#pragma unroll
    for (int ti = 0; ti < 4; ++ti)
        aq[ti] = *(const bf16x8*)(qb + (ti * 16 + lr) * 32 + lg * 8);
#pragma unroll
    for (int tj = 0; tj < 4; ++tj)
        bk[tj] = *(const bf16x8*)(kb_ + (tj * 16 + lr) * 32 + lg * 8);

    // ---------- S = Q K^T + softmax ----------
    f32x4 sH[4][4];
    __builtin_amdgcn_s_setprio(1);
#pragma unroll
    for (int ti = 0; ti < 4; ++ti)
#pragma unroll
        for (int tj = 0; tj < 4; ++tj)
            sH[ti][tj] = __builtin_amdgcn_mfma_f32_16x16x32_bf16(aq[ti], bk[tj], zero, 0, 0, 0);
    __builtin_amdgcn_s_setprio(0);

#pragma unroll
    for (int ti = 0; ti < 4; ++ti)
#pragma unroll
        for (int e = 0; e < 4; ++e) {
            int row = ti * 16 + lg * 4 + e;
            f16v4 mv = *(const f16x4*)(smem + moff + row * 128 + ((lr * 8) ^ ((row & 7) << 4)));
#pragma unroll
            for (int tj = 0; tj < 4; ++tj)
                sH[ti][tj][e] = sH[ti][tj][e] * scale + (float)mv[tj];
        }
    float inv[4][4];
#pragma unroll
    for (int ti = 0; ti < 4; ++ti)
#pragma unroll
        for (int e = 0; e < 4; ++e) {
            float v0 = sH[ti][0][e], v1 = sH[ti][1][e];
            float v2 = sH[ti][2][e], v3 = sH[ti][3][e];
            float m = fmaxf(fmaxf(v0, v1), fmaxf(v2, v3));
#pragma unroll
            for (int d = 1; d < 16; d <<= 1) m = fmaxf(m, __shfl_xor(m, d));
            v0 = __expf(v0 - m); v1 = __expf(v1 - m);
            v2 = __expf(v2 - m); v3 = __expf(v3 - m);
            float s = v0 + v1 + v2 + v3;
#pragma unroll
            for (int d = 1; d < 16; d <<= 1) s += __shfl_xor(s, d);
            inv[ti][e] = 1.0f / s;
            sH[ti][0][e] = v0; sH[ti][1][e] = v1;
            sH[ti][2][e] = v2; sH[ti][3][e] = v3;
        }
    u32 pkP[4][4][2];
#pragma unroll
    for (int ti = 0; ti < 4; ++ti)
#pragma unroll
        for (int tj = 0; tj < 4; ++tj) {
            pkP[ti][tj][0] = cvtpk(sH[ti][tj][0], sH[ti][tj][1]);
            pkP[ti][tj][1] = cvtpk(sH[ti][tj][2], sH[ti][tj][3]);
        }

    // ---------- PV in two k-halves ----------
    f32x4 oH[4][2];
#pragma unroll
    for (int ti = 0; ti < 4; ++ti)
#pragma unroll
        for (int tjv = 0; tjv < 2; ++tjv) oH[ti][tjv] = zero;
#pragma unroll
    for (int kb2 = 0; kb2 < 2; ++kb2) {
#pragma unroll
        for (int ti = 0; ti < 4; ++ti)
#pragma unroll
            for (int tjh = 0; tjh < 2; ++tjh) {
                int c2 = (tjh * 16 + lr) * 2;
#pragma unroll
                for (int ep = 0; ep < 2; ++ep) {
                    u32 u = pkP[ti][2 * kb2 + tjh][ep];
                    int q0 = ti * 16 + lg * 4 + ep * 2;
                    *(u16*)(smem + chunk + q0 * 64 + (c2 ^ (((q0 >> 1) & 3) << 4))) = (unsigned short)u;
                    *(u16*)(smem + chunk + (q0 + 1) * 64 + (c2 ^ ((((q0 + 1) >> 1) & 3) << 4))) = (unsigned short)(u >> 16);
                }
            }
        MEMFENCE();
        bf16v8 bv[2];
#pragma unroll
        for (int tjv = 0; tjv < 2; ++tjv) {
            int dh = tjv * 16 + lr;
            bv[tjv] = *(const bf16x8*)(vb + dh * 128 + kb2 * 64 + lg * 16);
        }
#pragma unroll
        for (int ti = 0; ti < 4; ++ti) {
            int row = ti * 16 + lr;
            bf16v8 ap = *(const bf16x8*)(smem + chunk + row * 64 + ((lg * 16) ^ (((row >> 1) & 3) << 4)));
            __builtin_amdgcn_s_setprio(1);
#pragma unroll
            for (int tjv = 0; tjv < 2; ++tjv)
                oH[ti][tjv] = __builtin_amdgcn_mfma_f32_16x16x32_bf16(ap, bv[tjv], oH[ti][tjv], 0, 0, 0);
            __builtin_amdgcn_s_setprio(0);
        }
        MEMFENCE();
    }
#pragma unroll
    for (int ti = 0; ti < 4; ++ti)
#pragma unroll
        for (int tjv = 0; tjv < 2; ++tjv)
#pragma unroll
            for (int e = 0; e < 4; ++e)
                oH[ti][tjv][e] *= inv[ti][e];

    __syncthreads();   // #2

    // ---------- stage O -> O_lds[64][256] ----------
#pragma unroll
    for (int ti = 0; ti < 4; ++ti)
#pragma unroll
        for (int tjv = 0; tjv < 2; ++tjv)
#pragma unroll
            for (int e = 0; e < 4; ++e) {
                int row = ti * 16 + lg * 4 + e;
                int cg  = hc + tjv * 16 + lr;
                *(u16*)(smem + row * 512 + ((cg * 2) ^ ((row & 7) << 4)))
                    = f2b(oH[ti][tjv][e]);
            }
    __syncthreads();   // #3

    // ---------- output projection (frag-major wpt) ----------
    f32x4 pacc[4][2];
#pragma unroll
    for (int ti = 0; ti < 4; ++ti)
#pragma unroll
        for (int tj = 0; tj < 2; ++tj) pacc[ti][tj] = zero;
#pragma unroll
    for (int ks = 0; ks < 8; ++ks) {
        bf16v8 a_[4];
#pragma unroll
        for (int ti = 0; ti < 4; ++ti) {
            int row = ti * 16 + lr;
            a_[ti] = *(const bf16x8*)(smem + row * 512 + ((ks * 64 + lg * 16) ^ ((row & 7) << 4)));
        }
        bf16v8 bw[2];
#pragma unroll
        for (int tj = 0; tj < 2; ++tj)
            bw[tj] = *(const bf16x8*)(wpt + (size_t)w * 8192 + tj * 4096 + ks * 512 + l * 8);
        __builtin_amdgcn_s_setprio(1);
#pragma unroll
        for (int tj = 0; tj < 2; ++tj)
#pragma unroll
            for (int ti = 0; ti < 4; ++ti)
                pacc[ti][tj] = __builtin_amdgcn_mfma_f32_16x16x32_bf16(a_[ti], bw[tj], pacc[ti][tj], 0, 0, 0);
        __builtin_amdgcn_s_setprio(0);
    }
    float* ob = out + (size_t)b * 16384;
#pragma unroll
    for (int tj = 0; tj < 2; ++tj) {
        float bias = bp[hc + tj * 16 + lr];
#pragma unroll
        for (int ti = 0; ti < 4; ++ti)
#pragma unroll
            for (int e = 0; e < 4; ++e) {
                int row = ti * 16 + lg * 4 + e;
                ob[row * 256 + hc + tj * 16 + lr] = pacc[ti][tj][e] + bias;
            }
    }
}

extern "C" void kernel_launch(void* const* d_in, const int* in_sizes, int n_in,
                              void* d_out, int out_size, void* d_ws, size_t ws_size,
                              hipStream_t stream) {
    const float* x    = (const float*)d_in[0];
    const float* mask = (const float*)d_in[1];
    const float* Wq   = (const float*)d_in[2];
    const float* bq   = (const float*)d_in[3];
    const float* Wkv  = (const float*)d_in[4];
    const float* bkv  = (const float*)d_in[5];
    const float* Wp   = (const float*)d_in[6];
    const float* bp   = (const float*)d_in[7];
    float* out = (float*)d_out;

    u16*   wt    = (u16*)d_ws;                    // 196608 u16 (frag-major)
    u16*   wpt   = wt + 196608;                   // 65536 u16 (frag-major)
    float* b_all = (float*)(wpt + 65536);         // 768 f32

    const size_t qkv_off   = 589824;              // bytes
    u16* qkv = (u16*)((unsigned char*)d_ws + qkv_off);

    prep_weights<<<1027, 256, 0, stream>>>(Wq, Wkv, Wp, bq, bkv, wt, wpt, b_all);
    qkv_proj<<<1024, 512, 0, stream>>>(x, wt, b_all, qkv);
    attn_out<<<2048, 512, 0, stream>>>(qkv, mask, wpt, bp, out);
}